// Round 12
// baseline (8003.089 us; speedup 1.0000x reference)
//
#include <hip/hip_runtime.h>
#include <hip/hip_bf16.h>

#define N_PTS 16384
#define DIM   128

typedef __bf16 bf16x8 __attribute__((ext_vector_type(8)));
typedef float  f32x4  __attribute__((ext_vector_type(4)));
typedef float  f32x16 __attribute__((ext_vector_type(16)));

// Monotone map float -> uint so unsigned atomicMin == float min (handles negatives).
__device__ __forceinline__ unsigned fmap(float f) {
    unsigned u = __float_as_uint(f);
    return (u & 0x80000000u) ? ~u : (u | 0x80000000u);
}
__device__ __forceinline__ float funmap(unsigned u) {
    return __uint_as_float((u & 0x80000000u) ? (u & 0x7FFFFFFFu) : ~u);
}

__device__ __forceinline__ void gload_lds16(const void* g, void* l) {
    __builtin_amdgcn_global_load_lds(
        (const __attribute__((address_space(1))) void*)g,
        (__attribute__((address_space(3))) void*)l, 16, 0, 0);
}

// B-side norm fragment for k=128..143: hi=0 lanes {b2hi,b2lo,1,1,0...}, hi=1 zeros.
__device__ __forceinline__ bf16x8 make_b2frag(unsigned p, int hi) {
    uint4 u;
    u.x = hi ? 0u : p;
    u.y = hi ? 0u : 0x3F803F80u;
    u.z = 0u; u.w = 0u;
    return __builtin_bit_cast(bf16x8, u);
}

// ---------------------------------------------------------------------------
// Prep v12: cloud1 -> Ax row-major bf16(-2*a) (128/row).
// cloud2 -> Bt2 col-block-tiled: col c -> cb=c>>5, lc=c&31; k-chunk ch=k>>3;
//   byte((cb*16+ch)*32 + lc)*16. One col-block = 16 chunks x 32 cols x 16B =
//   8KB, so a GEMM iteration's 8 loads are base + ks*1024 (immediates).
// Norms packed u32 (bf16 hi | lo<<16); aug k-step built in regs in the GEMM:
// dot = -2a.b + a2 + b2 = dist^2 (numerics verified rounds 4-10).
// Inits the 8*N min buffer (4 row slices + 4 col slices).
// ---------------------------------------------------------------------------
__global__ void chamfer_prep12(const float* __restrict__ A, const float* __restrict__ B,
                               unsigned short* __restrict__ Ax, unsigned char* __restrict__ Bt2,
                               unsigned* __restrict__ a2pack, unsigned* __restrict__ b2pack,
                               unsigned* __restrict__ minbuf) {
    int gtid = blockIdx.x * 256 + threadIdx.x;
    if (gtid < 8 * N_PTS) minbuf[gtid] = 0xFFFFFFFFu;

    int wave = blockIdx.x * 4 + (threadIdx.x >> 6);
    int lane = threadIdx.x & 63;
    int isB  = wave >= N_PTS;
    int row  = isB ? (wave - N_PTS) : wave;
    const float* src = isB ? B : A;

    float2 v = *reinterpret_cast<const float2*>(&src[(size_t)row * DIM + lane * 2]);
    float sc = isB ? 1.f : -2.f;
    __bf16 bx = (__bf16)(sc * v.x), by = (__bf16)(sc * v.y);
    ushort2 st;
    st.x = __builtin_bit_cast(unsigned short, bx);
    st.y = __builtin_bit_cast(unsigned short, by);

    if (!isB) {
        *reinterpret_cast<ushort2*>(&Ax[(size_t)row * DIM + lane * 2]) = st;
    } else {
        // lane covers k = 2*lane, 2*lane+1 -> chunk = lane>>2, dword = lane&3
        unsigned pd = (unsigned)st.x | ((unsigned)st.y << 16);
        int cb = row >> 5, lc = row & 31;
        *reinterpret_cast<unsigned*>(Bt2 +
            ((size_t)(cb * 16 + (lane >> 2)) * 32 + lc) * 16 + (lane & 3) * 4) = pd;
    }

    float s = fmaf(v.x, v.x, v.y * v.y);
    #pragma unroll
    for (int off = 1; off < 64; off <<= 1) s += __shfl_xor(s, off);

    if (lane == 0) {
        __bf16 hb = (__bf16)s;
        float  hf = (float)hb;
        __bf16 lb = (__bf16)(s - hf);
        unsigned hu = __builtin_bit_cast(unsigned short, hb);
        unsigned lu = __builtin_bit_cast(unsigned short, lb);
        (isB ? b2pack : a2pack)[row] = hu | (lu << 16);
    }
}

// ---------------------------------------------------------------------------
// GEMM+min v12 = v11 structure with the unroll blunder removed:
// 2048 blocks x 256 threads = 4 INDEPENDENT waves (no barriers, no LDS).
// Wave w of block b: rows [(b>>5)*256 + w*64, +64), col group g=b&31
// (512 cols = 16 col-blocks), 16 iters of 32 cols. 4 blocks/CU -> 16
// waves/CU (launch_bounds(256,4): cap=128 VGPR, live set measured 128 in
// v10, no spill). OUTER LOOP KEPT ROLLED (#pragma unroll 1) -- full unroll
// was the v11 spill cause. 4 waves/block read the same B col-block per
// iter -> L1 reuse. 2-deep register double-buffered B; fragment offsets
// are compile-time immediates off one per-iter base.
// C/D (32x32x16): col=lane&31, row=(reg&3)+8*(reg>>2)+4*(lane>>5).
// ---------------------------------------------------------------------------
__global__ __launch_bounds__(256, 4)
void chamfer_gemm_min12(const unsigned short* __restrict__ Ax,
                        const unsigned char* __restrict__ Bt2,
                        const unsigned* __restrict__ a2pack,
                        const unsigned* __restrict__ b2pack,
                        unsigned* __restrict__ rowminS,    // [4][N_PTS]
                        unsigned* __restrict__ colminS) {  // [4][N_PTS]
    const int b    = blockIdx.x;          // 2048
    const int g    = b & 31;              // col group (512 cols)
    const int mrow = b >> 5;              // 0..63
    const int w    = threadIdx.x >> 6;
    const int lane = threadIdx.x & 63;
    const int ll = lane & 31, hi = lane >> 5;
    const int tm   = mrow * 256 + w * 64;
    const int col0 = g * 512;

    // ---- A fragments -> registers (data ks 0..7 + register-built ks 8) ----
    bf16x8 af[2][9];
    #pragma unroll
    for (int mi = 0; mi < 2; ++mi) {
        const int row = tm + mi * 32 + ll;
        const unsigned short* ap = Ax + (size_t)row * DIM + hi * 8;
        #pragma unroll
        for (int ks = 0; ks < 8; ++ks)
            af[mi][ks] = *reinterpret_cast<const bf16x8*>(ap + ks * 16);
        unsigned apk = a2pack[row];
        uint4 au;
        au.x = hi ? 0u : 0x3F803F80u;   // {1,1}
        au.y = hi ? 0u : apk;           // {a2hi,a2lo}
        au.z = 0u; au.w = 0u;
        af[mi][8] = __builtin_bit_cast(bf16x8, au);
    }

    // per-lane bases: fragment ks at bbase + IT*8192 + ks*1024 (chunk 2ks+hi)
    const unsigned char* bbase = Bt2 + (size_t)(g * 16) * 8192 + hi * 512 + ll * 16;
    const unsigned* b2base = b2pack + col0 + ll;
    unsigned* colbase = colminS + (size_t)w * N_PTS + col0 + ll;   // slice = w

    float rmin_part[32];
    #pragma unroll
    for (int k = 0; k < 32; ++k) rmin_part[k] = 3.4e38f;

    bf16x8 bA[8], bB[8], b2A, b2B;

#define LOADB12(BUF, B2, IT) { \
    const unsigned char* _bp = bbase + (size_t)(IT) * 8192; \
    _Pragma("unroll") \
    for (int _ks = 0; _ks < 8; ++_ks) \
        BUF[_ks] = *reinterpret_cast<const bf16x8*>(_bp + _ks * 1024); \
    B2 = make_b2frag(b2base[(IT) * 32], hi); }

#define COMPUTE12(BUF, B2, IT) { \
    __builtin_amdgcn_s_setprio(1); \
    f32x16 _a0 = {}, _a1 = {}; \
    _Pragma("unroll") \
    for (int _ks = 0; _ks < 8; ++_ks) { \
        _a0 = __builtin_amdgcn_mfma_f32_32x32x16_bf16(af[0][_ks], BUF[_ks], _a0, 0, 0, 0); \
        _a1 = __builtin_amdgcn_mfma_f32_32x32x16_bf16(af[1][_ks], BUF[_ks], _a1, 0, 0, 0); \
    } \
    _a0 = __builtin_amdgcn_mfma_f32_32x32x16_bf16(af[0][8], B2, _a0, 0, 0, 0); \
    _a1 = __builtin_amdgcn_mfma_f32_32x32x16_bf16(af[1][8], B2, _a1, 0, 0, 0); \
    __builtin_amdgcn_s_setprio(0); \
    float _cm = fminf(_a0[0], _a1[0]); \
    _Pragma("unroll") \
    for (int _r = 0; _r < 16; ++_r) { \
        rmin_part[_r]      = fminf(rmin_part[_r],      _a0[_r]); \
        rmin_part[16 + _r] = fminf(rmin_part[16 + _r], _a1[_r]); \
        if (_r) _cm = fminf(_cm, fminf(_a0[_r], _a1[_r])); \
    } \
    _cm = fminf(_cm, __shfl_xor(_cm, 32)); \
    if (hi == 0) atomicMin(colbase + (IT) * 32, fmap(_cm)); }

    // ---- prologue: 2 iterations of B in flight ----
    LOADB12(bA, b2A, 0)
    LOADB12(bB, b2B, 1)

    #pragma unroll 1
    for (int i2 = 0; i2 < 8; ++i2) {
        const int it = i2 * 2;
        COMPUTE12(bA, b2A, it)
        if (it + 2 < 16) LOADB12(bA, b2A, it + 2)
        COMPUTE12(bB, b2B, it + 1)
        if (it + 3 < 16) LOADB12(bB, b2B, it + 3)
    }
#undef LOADB12
#undef COMPUTE12

    // ---- final row reduce-scatter: 32 vars over 32 ll-lanes, 5 stages ----
    #pragma unroll
    for (int s = 16; s >= 1; s >>= 1) {
        #pragma unroll
        for (int k = 0; k < 16; ++k) {
            if (k < s) {
                float snd = (ll & s) ? rmin_part[k] : rmin_part[k + s];
                float r = __shfl_xor(snd, s);
                rmin_part[k] = (ll & s) ? fminf(rmin_part[k + s], r) : fminf(rmin_part[k], r);
            }
        }
    }
    const int own_row = tm + ((ll >> 4) << 5) + (ll & 3) + (((ll >> 2) & 3) << 3) + (hi << 2);
    atomicMin(&rowminS[(size_t)(g & 3) * N_PTS + own_row], fmap(rmin_part[0]));
}

// ---------------------------------------------------------------------------
// Finalize, two-stage: rows min over 4 slices, cols min over 4; double sums.
// ---------------------------------------------------------------------------
__global__ void chamfer_partial12(const unsigned* __restrict__ rowminS,
                                  const unsigned* __restrict__ colminS,
                                  double* __restrict__ partials) {
    __shared__ double sred[4];
    int t = threadIdx.x;
    int i = blockIdx.x * 256 + t;
    unsigned rm = min(min(rowminS[i],             rowminS[i + N_PTS]),
                      min(rowminS[i + 2 * N_PTS], rowminS[i + 3 * N_PTS]));
    unsigned cm = min(min(colminS[i],             colminS[i + N_PTS]),
                      min(colminS[i + 2 * N_PTS], colminS[i + 3 * N_PTS]));
    double s = (double)funmap(rm) + (double)funmap(cm);
    #pragma unroll
    for (int off = 32; off; off >>= 1) s += __shfl_down(s, off);
    if ((t & 63) == 0) sred[t >> 6] = s;
    __syncthreads();
    if (t == 0) partials[blockIdx.x] = sred[0] + sred[1] + sred[2] + sred[3];
}

__global__ void chamfer_final12(const double* __restrict__ partials,
                                float* __restrict__ out) {
    int t = threadIdx.x;   // 64 threads
    double s = partials[t];
    #pragma unroll
    for (int off = 32; off; off >>= 1) s += __shfl_down(s, off);
    if (t == 0) out[0] = (float)(s * (1.0 / (double)N_PTS));
}

// ---------------------------------------------------------------------------
// Fallback path = round-3 kernels (known-passing) if ws too small.
// ---------------------------------------------------------------------------
__global__ void chamfer_prep2(const float* __restrict__ A, const float* __restrict__ B,
                              unsigned short* __restrict__ Abf, unsigned short* __restrict__ Bbf,
                              float* __restrict__ a2, float* __restrict__ b2,
                              unsigned* __restrict__ rowmin, unsigned* __restrict__ colmin) {
    int wave = blockIdx.x * 4 + (threadIdx.x >> 6);
    int lane = threadIdx.x & 63;
    int isB  = wave >= N_PTS;
    int row  = isB ? (wave - N_PTS) : wave;
    const float* src = isB ? B : A;
    unsigned short* dst = isB ? Bbf : Abf;

    float2 v = *reinterpret_cast<const float2*>(&src[(size_t)row * DIM + lane * 2]);
    __bf16 bx = (__bf16)v.x, by = (__bf16)v.y;
    ushort2 st;
    st.x = __builtin_bit_cast(unsigned short, bx);
    st.y = __builtin_bit_cast(unsigned short, by);
    *reinterpret_cast<ushort2*>(&dst[(size_t)row * DIM + lane * 2]) = st;

    float s = fmaf(v.x, v.x, v.y * v.y);
    #pragma unroll
    for (int off = 32; off; off >>= 1) s += __shfl_down(s, off);
    if (lane == 0) {
        if (isB) { b2[row] = s; colmin[row] = 0xFFFFFFFFu; }
        else     { a2[row] = s; rowmin[row] = 0xFFFFFFFFu; }
    }
}

__global__ __launch_bounds__(512, 2)
void chamfer_gemm_min3(const unsigned short* __restrict__ Abf, const unsigned short* __restrict__ Bbf,
                       const float* __restrict__ a2, const float* __restrict__ b2,
                       unsigned* __restrict__ rowmin, unsigned* __restrict__ colmin) {
    __shared__ __align__(16) unsigned char sA[65536];
    __shared__ __align__(16) unsigned char sB2[2][32768];

    const int b = blockIdx.x;
    const int tm_base = (b >> 2) * 256;
    const int tn0 = (b & 3) * 32;

    const int t = threadIdx.x;
    const int w = t >> 6, lane = t & 63;
    const int lq = lane >> 4, lr = lane & 15;
    const int wr = (w >> 1) * 64;
    const int wc = (w & 1) * 64;

    #pragma unroll
    for (int jj = 0; jj < 8; ++jj) {
        int chunk = ((w << 3) + jj) * 64 + lane;
        int r = chunk >> 4, kc = (chunk & 15) ^ (r & 7);
        gload_lds16(Abf + (size_t)(tm_base + r) * DIM + kc * 8, sA + chunk * 16);
    }
    #pragma unroll
    for (int jj = 0; jj < 4; ++jj) {
        int chunk = ((w << 2) + jj) * 64 + lane;
        int r = chunk >> 4, kc = (chunk & 15) ^ (r & 7);
        gload_lds16(Bbf + (size_t)(tn0 * 128 + r) * DIM + kc * 8, sB2[0] + chunk * 16);
    }

    float a2v[4][4];
    #pragma unroll
    for (int mi = 0; mi < 4; ++mi) {
        float4 q = *reinterpret_cast<const float4*>(&a2[tm_base + wr + mi * 16 + lq * 4]);
        a2v[mi][0] = q.x; a2v[mi][1] = q.y; a2v[mi][2] = q.z; a2v[mi][3] = q.w;
    }
    __syncthreads();

    for (int it = 0; it < 32; ++it) {
        const int cur = it & 1;
        const int tn = tn0 + it;

        if (it + 1 < 32) {
            #pragma unroll
            for (int jj = 0; jj < 4; ++jj) {
                int chunk = ((w << 2) + jj) * 64 + lane;
                int r = chunk >> 4, kc = (chunk & 15) ^ (r & 7);
                gload_lds16(Bbf + (size_t)((tn + 1) * 128 + r) * DIM + kc * 8,
                            sB2[cur ^ 1] + chunk * 16);
            }
        }

        f32x4 acc[4][4] = {};
        #pragma unroll
        for (int ks = 0; ks < 4; ++ks) {
            const int kc = ks * 4 + lq;
            bf16x8 af2[4], bfr[4];
            #pragma unroll
            for (int mi = 0; mi < 4; ++mi) {
                int r = wr + mi * 16 + lr;
                af2[mi] = *reinterpret_cast<const bf16x8*>(&sA[r * 256 + ((kc * 16) ^ ((r & 7) << 4))]);
            }
            #pragma unroll
            for (int ni = 0; ni < 4; ++ni) {
                int r = wc + ni * 16 + lr;
                bfr[ni] = *reinterpret_cast<const bf16x8*>(&sB2[cur][r * 256 + ((kc * 16) ^ ((r & 7) << 4))]);
            }
            #pragma unroll
            for (int mi = 0; mi < 4; ++mi)
                #pragma unroll
                for (int ni = 0; ni < 4; ++ni)
                    acc[mi][ni] = __builtin_amdgcn_mfma_f32_16x16x32_bf16(af2[mi], bfr[ni], acc[mi][ni], 0, 0, 0);
        }

        const int col_base = tn * 128 + wc;
        float b2v[4];
        #pragma unroll
        for (int ni = 0; ni < 4; ++ni) b2v[ni] = b2[col_base + ni * 16 + lr];

        float v[16];
        #pragma unroll
        for (int mi = 0; mi < 4; ++mi) {
            #pragma unroll
            for (int jj = 0; jj < 4; ++jj) {
                float m = fmaf(-2.f, acc[mi][0][jj], b2v[0]);
                m = fminf(m, fmaf(-2.f, acc[mi][1][jj], b2v[1]));
                m = fminf(m, fmaf(-2.f, acc[mi][2][jj], b2v[2]));
                m = fminf(m, fmaf(-2.f, acc[mi][3][jj], b2v[3]));
                v[mi * 4 + jj] = m;
            }
        }
        #pragma unroll
        for (int k = 0; k < 8; ++k) {
            float s = (lr & 8) ? v[k] : v[k + 8];
            float r = __shfl_xor(s, 8);
            v[k] = (lr & 8) ? fminf(v[k + 8], r) : fminf(v[k], r);
        }
        #pragma unroll
        for (int k = 0; k < 4; ++k) {
            float s = (lr & 4) ? v[k] : v[k + 4];
            float r = __shfl_xor(s, 4);
            v[k] = (lr & 4) ? fminf(v[k + 4], r) : fminf(v[k], r);
        }
        #pragma unroll
        for (int k = 0; k < 2; ++k) {
            float s = (lr & 2) ? v[k] : v[k + 2];
            float r = __shfl_xor(s, 2);
            v[k] = (lr & 2) ? fminf(v[k + 2], r) : fminf(v[k], r);
        }
        {
            float s = (lr & 1) ? v[0] : v[1];
            float r = __shfl_xor(s, 1);
            v[0] = (lr & 1) ? fminf(v[1], r) : fminf(v[0], r);
        }
        const int own_row = tm_base + wr + ((lr >> 2) << 4) + (lq << 2) + (lr & 3);

        float cp[4];
        #pragma unroll
        for (int ni = 0; ni < 4; ++ni) {
            float m = fmaf(-2.f, acc[0][ni][0], a2v[0][0]);
            #pragma unroll
            for (int mi = 0; mi < 4; ++mi)
                #pragma unroll
                for (int jj = 0; jj < 4; ++jj)
                    if (mi | jj) m = fminf(m, fmaf(-2.f, acc[mi][ni][jj], a2v[mi][jj]));
            cp[ni] = m;
        }
        #pragma unroll
        for (int k = 0; k < 2; ++k) {
            float s = (lane & 16) ? cp[k] : cp[k + 2];
            float r = __shfl_xor(s, 16);
            cp[k] = (lane & 16) ? fminf(cp[k + 2], r) : fminf(cp[k], r);
        }
        float cfin;
        {
            float s = (lane & 32) ? cp[0] : cp[1];
            float r = __shfl_xor(s, 32);
            cfin = (lane & 32) ? fminf(cp[1], r) : fminf(cp[0], r);
        }
        const int ni_own = ((lq & 1) << 1) | (lq >> 1);
        const int own_col = col_base + ni_own * 16 + lr;

        __syncthreads();

        atomicMin(&rowmin[own_row], fmap(v[0]));
        atomicMin(&colmin[own_col], fmap(cfin));
    }
}

__global__ void chamfer_finalize2(const unsigned* __restrict__ rowmin,
                                  const unsigned* __restrict__ colmin,
                                  const float* __restrict__ a2, const float* __restrict__ b2,
                                  float* __restrict__ out) {
    __shared__ double sred[16];
    int t = threadIdx.x;
    double s = 0.0;
    for (int i = t; i < N_PTS; i += 1024)
        s += ((double)funmap(rowmin[i]) + (double)a2[i])
           + ((double)funmap(colmin[i]) + (double)b2[i]);
    #pragma unroll
    for (int off = 32; off; off >>= 1) s += __shfl_down(s, off);
    if ((t & 63) == 0) sred[t >> 6] = s;
    __syncthreads();
    if (t == 0) {
        double tot = 0.0;
        #pragma unroll
        for (int i = 0; i < 16; ++i) tot += sred[i];
        out[0] = (float)(tot * (1.0 / (double)N_PTS));
    }
}

// ---------------------------------------------------------------------------
extern "C" void kernel_launch(void* const* d_in, const int* in_sizes, int n_in,
                              void* d_out, int out_size, void* d_ws, size_t ws_size,
                              hipStream_t stream) {
    const float* A = (const float*)d_in[0];
    const float* B = (const float*)d_in[1];
    float* out = (float*)d_out;
    char* ws = (char*)d_ws;

    const size_t MATSZ  = (size_t)N_PTS * DIM * sizeof(unsigned short);  // 4 MB
    const size_t PKSZ   = (size_t)N_PTS * 4;                             // 64 KB
    const size_t need12 = 2 * MATSZ + 2 * PKSZ + 8 * PKSZ + 64 * sizeof(double);

    const size_t need3  = 2 * MATSZ + 4 * (size_t)(1 << 16);             // ~8.65 MB

    if (ws_size >= need12) {
        unsigned short* Ax  = (unsigned short*)(ws);
        unsigned char*  Bt2 = (unsigned char*)(ws + MATSZ);
        unsigned* a2pack    = (unsigned*)(ws + 2 * MATSZ);
        unsigned* b2pack    = (unsigned*)(ws + 2 * MATSZ + PKSZ);
        unsigned* minbuf    = (unsigned*)(ws + 2 * MATSZ + 2 * PKSZ);
        unsigned* rowminS   = minbuf;                     // [4][N]
        unsigned* colminS   = minbuf + 4 * N_PTS;         // [4][N]
        double*   partials  = (double*)(ws + 2 * MATSZ + 10 * PKSZ);

        chamfer_prep12<<<(2 * N_PTS) / 4, 256, 0, stream>>>(A, B, Ax, Bt2, a2pack, b2pack, minbuf);
        chamfer_gemm_min12<<<2048, 256, 0, stream>>>(Ax, Bt2, a2pack, b2pack, rowminS, colminS);
        chamfer_partial12<<<64, 256, 0, stream>>>(rowminS, colminS, partials);
        chamfer_final12<<<1, 64, 0, stream>>>(partials, out);
    } else if (ws_size >= need3) {
        unsigned short* Abf = (unsigned short*)(ws);
        unsigned short* Bbf = (unsigned short*)(ws + MATSZ);
        float*    a2     = (float*)(ws + 2 * MATSZ);
        float*    b2     = (float*)(ws + 2 * MATSZ + (1 << 16));
        unsigned* rowmin = (unsigned*)(ws + 2 * MATSZ + (2 << 16));
        unsigned* colmin = (unsigned*)(ws + 2 * MATSZ + (3 << 16));

        chamfer_prep2<<<(2 * N_PTS) / 4, 256, 0, stream>>>(A, B, Abf, Bbf, a2, b2, rowmin, colmin);
        chamfer_gemm_min3<<<256, 512, 0, stream>>>(Abf, Bbf, a2, b2, rowmin, colmin);
        chamfer_finalize2<<<1, 1024, 0, stream>>>(rowmin, colmin, a2, b2, out);
    }
}

// Round 13
// 192.900 us; speedup vs baseline: 41.4882x; 41.4882x over previous
//
#include <hip/hip_runtime.h>
#include <hip/hip_bf16.h>

#define N_PTS 16384
#define DIM   128

typedef __bf16 bf16x8 __attribute__((ext_vector_type(8)));
typedef float  f32x4  __attribute__((ext_vector_type(4)));
typedef float  f32x16 __attribute__((ext_vector_type(16)));

// Monotone map float -> uint so unsigned atomicMin == float min (handles negatives).
__device__ __forceinline__ unsigned fmap(float f) {
    unsigned u = __float_as_uint(f);
    return (u & 0x80000000u) ? ~u : (u | 0x80000000u);
}
__device__ __forceinline__ float funmap(unsigned u) {
    return __uint_as_float((u & 0x80000000u) ? (u & 0x7FFFFFFFu) : ~u);
}

__device__ __forceinline__ void gload_lds16(const void* g, void* l) {
    __builtin_amdgcn_global_load_lds(
        (const __attribute__((address_space(1))) void*)g,
        (__attribute__((address_space(3))) void*)l, 16, 0, 0);
}

// B-side norm fragment for k=128..143: hi=0 lanes {b2hi,b2lo,1,1,0...}, hi=1 zeros.
__device__ __forceinline__ bf16x8 make_b2frag(unsigned p, int hi) {
    uint4 u;
    u.x = hi ? 0u : p;
    u.y = hi ? 0u : 0x3F803F80u;
    u.z = 0u; u.w = 0u;
    return __builtin_bit_cast(bf16x8, u);
}

// ---------------------------------------------------------------------------
// Prep v13: cloud1 -> Ax row-major bf16(-2*a) (128/row).
// cloud2 -> Bt2 col-block-tiled: col c -> cb=c>>5, lc=c&31; k-chunk ch=k>>3;
//   byte((cb*16+ch)*32 + lc)*16. One col-block = 16 chunks x 32 cols x 16B =
//   8KB, so a GEMM iteration's 8 loads are base + ks*1024 (immediates).
// Norms packed u32 (bf16 hi | lo<<16); aug k-step built in regs in the GEMM:
// dot = -2a.b + a2 + b2 = dist^2 (numerics verified rounds 4-10).
// Inits the 8*N min buffer (4 row slices + 4 col slices).
// ---------------------------------------------------------------------------
__global__ void chamfer_prep13(const float* __restrict__ A, const float* __restrict__ B,
                               unsigned short* __restrict__ Ax, unsigned char* __restrict__ Bt2,
                               unsigned* __restrict__ a2pack, unsigned* __restrict__ b2pack,
                               unsigned* __restrict__ minbuf) {
    int gtid = blockIdx.x * 256 + threadIdx.x;
    if (gtid < 8 * N_PTS) minbuf[gtid] = 0xFFFFFFFFu;

    int wave = blockIdx.x * 4 + (threadIdx.x >> 6);
    int lane = threadIdx.x & 63;
    int isB  = wave >= N_PTS;
    int row  = isB ? (wave - N_PTS) : wave;
    const float* src = isB ? B : A;

    float2 v = *reinterpret_cast<const float2*>(&src[(size_t)row * DIM + lane * 2]);
    float sc = isB ? 1.f : -2.f;
    __bf16 bx = (__bf16)(sc * v.x), by = (__bf16)(sc * v.y);
    ushort2 st;
    st.x = __builtin_bit_cast(unsigned short, bx);
    st.y = __builtin_bit_cast(unsigned short, by);

    if (!isB) {
        *reinterpret_cast<ushort2*>(&Ax[(size_t)row * DIM + lane * 2]) = st;
    } else {
        // lane covers k = 2*lane, 2*lane+1 -> chunk = lane>>2, dword = lane&3
        unsigned pd = (unsigned)st.x | ((unsigned)st.y << 16);
        int cb = row >> 5, lc = row & 31;
        *reinterpret_cast<unsigned*>(Bt2 +
            ((size_t)(cb * 16 + (lane >> 2)) * 32 + lc) * 16 + (lane & 3) * 4) = pd;
    }

    float s = fmaf(v.x, v.x, v.y * v.y);
    #pragma unroll
    for (int off = 1; off < 64; off <<= 1) s += __shfl_xor(s, off);

    if (lane == 0) {
        __bf16 hb = (__bf16)s;
        float  hf = (float)hb;
        __bf16 lb = (__bf16)(s - hf);
        unsigned hu = __builtin_bit_cast(unsigned short, hb);
        unsigned lu = __builtin_bit_cast(unsigned short, lb);
        (isB ? b2pack : a2pack)[row] = hu | (lu << 16);
    }
}

// ---------------------------------------------------------------------------
// GEMM+min v13 = v12 WITHOUT the occupancy cap (the v12 spill cause):
// __launch_bounds__(256) only -- live set needs ~230 unified regs, so never
// pass a min-waves argument (lesson from rounds 8/11/12).
// 2048 blocks x 256 threads = 4 INDEPENDENT waves (no barriers, no LDS).
// Wave w of block b: rows [(b>>5)*256 + w*64, +64), col group g=b&31
// (512 cols = 16 col-blocks), 16 iters of 32 cols. The 4 waves read the
// same B col-block per iter -> L1 reuse. 2-deep register double-buffered B;
// fragment offsets are compile-time immediates off one per-iter base.
// Outer loop kept ROLLED (#pragma unroll 1) -- full unroll was v11's spill.
// C/D (32x32x16): col=lane&31, row=(reg&3)+8*(reg>>2)+4*(lane>>5).
// ---------------------------------------------------------------------------
__global__ __launch_bounds__(256)
void chamfer_gemm_min13(const unsigned short* __restrict__ Ax,
                        const unsigned char* __restrict__ Bt2,
                        const unsigned* __restrict__ a2pack,
                        const unsigned* __restrict__ b2pack,
                        unsigned* __restrict__ rowminS,    // [4][N_PTS]
                        unsigned* __restrict__ colminS) {  // [4][N_PTS]
    const int b    = blockIdx.x;          // 2048
    const int g    = b & 31;              // col group (512 cols)
    const int mrow = b >> 5;              // 0..63
    const int w    = threadIdx.x >> 6;
    const int lane = threadIdx.x & 63;
    const int ll = lane & 31, hi = lane >> 5;
    const int tm   = mrow * 256 + w * 64;
    const int col0 = g * 512;

    // ---- A fragments -> registers (data ks 0..7 + register-built ks 8) ----
    bf16x8 af[2][9];
    #pragma unroll
    for (int mi = 0; mi < 2; ++mi) {
        const int row = tm + mi * 32 + ll;
        const unsigned short* ap = Ax + (size_t)row * DIM + hi * 8;
        #pragma unroll
        for (int ks = 0; ks < 8; ++ks)
            af[mi][ks] = *reinterpret_cast<const bf16x8*>(ap + ks * 16);
        unsigned apk = a2pack[row];
        uint4 au;
        au.x = hi ? 0u : 0x3F803F80u;   // {1,1}
        au.y = hi ? 0u : apk;           // {a2hi,a2lo}
        au.z = 0u; au.w = 0u;
        af[mi][8] = __builtin_bit_cast(bf16x8, au);
    }

    // per-lane bases: fragment ks at bbase + IT*8192 + ks*1024 (chunk 2ks+hi)
    const unsigned char* bbase = Bt2 + (size_t)(g * 16) * 8192 + hi * 512 + ll * 16;
    const unsigned* b2base = b2pack + col0 + ll;
    unsigned* colbase = colminS + (size_t)w * N_PTS + col0 + ll;   // slice = w

    float rmin_part[32];
    #pragma unroll
    for (int k = 0; k < 32; ++k) rmin_part[k] = 3.4e38f;

    bf16x8 bA[8], bB[8], b2A, b2B;

#define LOADB13(BUF, B2, IT) { \
    const unsigned char* _bp = bbase + (size_t)(IT) * 8192; \
    _Pragma("unroll") \
    for (int _ks = 0; _ks < 8; ++_ks) \
        BUF[_ks] = *reinterpret_cast<const bf16x8*>(_bp + _ks * 1024); \
    B2 = make_b2frag(b2base[(IT) * 32], hi); }

#define COMPUTE13(BUF, B2, IT) { \
    __builtin_amdgcn_s_setprio(1); \
    f32x16 _a0 = {}, _a1 = {}; \
    _Pragma("unroll") \
    for (int _ks = 0; _ks < 8; ++_ks) { \
        _a0 = __builtin_amdgcn_mfma_f32_32x32x16_bf16(af[0][_ks], BUF[_ks], _a0, 0, 0, 0); \
        _a1 = __builtin_amdgcn_mfma_f32_32x32x16_bf16(af[1][_ks], BUF[_ks], _a1, 0, 0, 0); \
    } \
    _a0 = __builtin_amdgcn_mfma_f32_32x32x16_bf16(af[0][8], B2, _a0, 0, 0, 0); \
    _a1 = __builtin_amdgcn_mfma_f32_32x32x16_bf16(af[1][8], B2, _a1, 0, 0, 0); \
    __builtin_amdgcn_s_setprio(0); \
    float _cm = fminf(_a0[0], _a1[0]); \
    _Pragma("unroll") \
    for (int _r = 0; _r < 16; ++_r) { \
        rmin_part[_r]      = fminf(rmin_part[_r],      _a0[_r]); \
        rmin_part[16 + _r] = fminf(rmin_part[16 + _r], _a1[_r]); \
        if (_r) _cm = fminf(_cm, fminf(_a0[_r], _a1[_r])); \
    } \
    _cm = fminf(_cm, __shfl_xor(_cm, 32)); \
    if (hi == 0) atomicMin(colbase + (IT) * 32, fmap(_cm)); }

    // ---- prologue: 2 iterations of B in flight ----
    LOADB13(bA, b2A, 0)
    LOADB13(bB, b2B, 1)

    #pragma unroll 1
    for (int i2 = 0; i2 < 8; ++i2) {
        const int it = i2 * 2;
        COMPUTE13(bA, b2A, it)
        if (it + 2 < 16) LOADB13(bA, b2A, it + 2)
        COMPUTE13(bB, b2B, it + 1)
        if (it + 3 < 16) LOADB13(bB, b2B, it + 3)
    }
#undef LOADB13
#undef COMPUTE13

    // ---- final row reduce-scatter: 32 vars over 32 ll-lanes, 5 stages ----
    #pragma unroll
    for (int s = 16; s >= 1; s >>= 1) {
        #pragma unroll
        for (int k = 0; k < 16; ++k) {
            if (k < s) {
                float snd = (ll & s) ? rmin_part[k] : rmin_part[k + s];
                float r = __shfl_xor(snd, s);
                rmin_part[k] = (ll & s) ? fminf(rmin_part[k + s], r) : fminf(rmin_part[k], r);
            }
        }
    }
    const int own_row = tm + ((ll >> 4) << 5) + (ll & 3) + (((ll >> 2) & 3) << 3) + (hi << 2);
    atomicMin(&rowminS[(size_t)(g & 3) * N_PTS + own_row], fmap(rmin_part[0]));
}

// ---------------------------------------------------------------------------
// Finalize, two-stage: rows min over 4 slices, cols min over 4; double sums.
// ---------------------------------------------------------------------------
__global__ void chamfer_partial13(const unsigned* __restrict__ rowminS,
                                  const unsigned* __restrict__ colminS,
                                  double* __restrict__ partials) {
    __shared__ double sred[4];
    int t = threadIdx.x;
    int i = blockIdx.x * 256 + t;
    unsigned rm = min(min(rowminS[i],             rowminS[i + N_PTS]),
                      min(rowminS[i + 2 * N_PTS], rowminS[i + 3 * N_PTS]));
    unsigned cm = min(min(colminS[i],             colminS[i + N_PTS]),
                      min(colminS[i + 2 * N_PTS], colminS[i + 3 * N_PTS]));
    double s = (double)funmap(rm) + (double)funmap(cm);
    #pragma unroll
    for (int off = 32; off; off >>= 1) s += __shfl_down(s, off);
    if ((t & 63) == 0) sred[t >> 6] = s;
    __syncthreads();
    if (t == 0) partials[blockIdx.x] = sred[0] + sred[1] + sred[2] + sred[3];
}

__global__ void chamfer_final13(const double* __restrict__ partials,
                                float* __restrict__ out) {
    int t = threadIdx.x;   // 64 threads
    double s = partials[t];
    #pragma unroll
    for (int off = 32; off; off >>= 1) s += __shfl_down(s, off);
    if (t == 0) out[0] = (float)(s * (1.0 / (double)N_PTS));
}

// ---------------------------------------------------------------------------
// Fallback path = round-3 kernels (known-passing) if ws too small.
// ---------------------------------------------------------------------------
__global__ void chamfer_prep2(const float* __restrict__ A, const float* __restrict__ B,
                              unsigned short* __restrict__ Abf, unsigned short* __restrict__ Bbf,
                              float* __restrict__ a2, float* __restrict__ b2,
                              unsigned* __restrict__ rowmin, unsigned* __restrict__ colmin) {
    int wave = blockIdx.x * 4 + (threadIdx.x >> 6);
    int lane = threadIdx.x & 63;
    int isB  = wave >= N_PTS;
    int row  = isB ? (wave - N_PTS) : wave;
    const float* src = isB ? B : A;
    unsigned short* dst = isB ? Bbf : Abf;

    float2 v = *reinterpret_cast<const float2*>(&src[(size_t)row * DIM + lane * 2]);
    __bf16 bx = (__bf16)v.x, by = (__bf16)v.y;
    ushort2 st;
    st.x = __builtin_bit_cast(unsigned short, bx);
    st.y = __builtin_bit_cast(unsigned short, by);
    *reinterpret_cast<ushort2*>(&dst[(size_t)row * DIM + lane * 2]) = st;

    float s = fmaf(v.x, v.x, v.y * v.y);
    #pragma unroll
    for (int off = 32; off; off >>= 1) s += __shfl_down(s, off);
    if (lane == 0) {
        if (isB) { b2[row] = s; colmin[row] = 0xFFFFFFFFu; }
        else     { a2[row] = s; rowmin[row] = 0xFFFFFFFFu; }
    }
}

__global__ __launch_bounds__(512, 2)
void chamfer_gemm_min3(const unsigned short* __restrict__ Abf, const unsigned short* __restrict__ Bbf,
                       const float* __restrict__ a2, const float* __restrict__ b2,
                       unsigned* __restrict__ rowmin, unsigned* __restrict__ colmin) {
    __shared__ __align__(16) unsigned char sA[65536];
    __shared__ __align__(16) unsigned char sB2[2][32768];

    const int b = blockIdx.x;
    const int tm_base = (b >> 2) * 256;
    const int tn0 = (b & 3) * 32;

    const int t = threadIdx.x;
    const int w = t >> 6, lane = t & 63;
    const int lq = lane >> 4, lr = lane & 15;
    const int wr = (w >> 1) * 64;
    const int wc = (w & 1) * 64;

    #pragma unroll
    for (int jj = 0; jj < 8; ++jj) {
        int chunk = ((w << 3) + jj) * 64 + lane;
        int r = chunk >> 4, kc = (chunk & 15) ^ (r & 7);
        gload_lds16(Abf + (size_t)(tm_base + r) * DIM + kc * 8, sA + chunk * 16);
    }
    #pragma unroll
    for (int jj = 0; jj < 4; ++jj) {
        int chunk = ((w << 2) + jj) * 64 + lane;
        int r = chunk >> 4, kc = (chunk & 15) ^ (r & 7);
        gload_lds16(Bbf + (size_t)(tn0 * 128 + r) * DIM + kc * 8, sB2[0] + chunk * 16);
    }

    float a2v[4][4];
    #pragma unroll
    for (int mi = 0; mi < 4; ++mi) {
        float4 q = *reinterpret_cast<const float4*>(&a2[tm_base + wr + mi * 16 + lq * 4]);
        a2v[mi][0] = q.x; a2v[mi][1] = q.y; a2v[mi][2] = q.z; a2v[mi][3] = q.w;
    }
    __syncthreads();

    for (int it = 0; it < 32; ++it) {
        const int cur = it & 1;
        const int tn = tn0 + it;

        if (it + 1 < 32) {
            #pragma unroll
            for (int jj = 0; jj < 4; ++jj) {
                int chunk = ((w << 2) + jj) * 64 + lane;
                int r = chunk >> 4, kc = (chunk & 15) ^ (r & 7);
                gload_lds16(Bbf + (size_t)((tn + 1) * 128 + r) * DIM + kc * 8,
                            sB2[cur ^ 1] + chunk * 16);
            }
        }

        f32x4 acc[4][4] = {};
        #pragma unroll
        for (int ks = 0; ks < 4; ++ks) {
            const int kc = ks * 4 + lq;
            bf16x8 af2[4], bfr[4];
            #pragma unroll
            for (int mi = 0; mi < 4; ++mi) {
                int r = wr + mi * 16 + lr;
                af2[mi] = *reinterpret_cast<const bf16x8*>(&sA[r * 256 + ((kc * 16) ^ ((r & 7) << 4))]);
            }
            #pragma unroll
            for (int ni = 0; ni < 4; ++ni) {
                int r = wc + ni * 16 + lr;
                bfr[ni] = *reinterpret_cast<const bf16x8*>(&sB2[cur][r * 256 + ((kc * 16) ^ ((r & 7) << 4))]);
            }
            #pragma unroll
            for (int mi = 0; mi < 4; ++mi)
                #pragma unroll
                for (int ni = 0; ni < 4; ++ni)
                    acc[mi][ni] = __builtin_amdgcn_mfma_f32_16x16x32_bf16(af2[mi], bfr[ni], acc[mi][ni], 0, 0, 0);
        }

        const int col_base = tn * 128 + wc;
        float b2v[4];
        #pragma unroll
        for (int ni = 0; ni < 4; ++ni) b2v[ni] = b2[col_base + ni * 16 + lr];

        float v[16];
        #pragma unroll
        for (int mi = 0; mi < 4; ++mi) {
            #pragma unroll
            for (int jj = 0; jj < 4; ++jj) {
                float m = fmaf(-2.f, acc[mi][0][jj], b2v[0]);
                m = fminf(m, fmaf(-2.f, acc[mi][1][jj], b2v[1]));
                m = fminf(m, fmaf(-2.f, acc[mi][2][jj], b2v[2]));
                m = fminf(m, fmaf(-2.f, acc[mi][3][jj], b2v[3]));
                v[mi * 4 + jj] = m;
            }
        }
        #pragma unroll
        for (int k = 0; k < 8; ++k) {
            float s = (lr & 8) ? v[k] : v[k + 8];
            float r = __shfl_xor(s, 8);
            v[k] = (lr & 8) ? fminf(v[k + 8], r) : fminf(v[k], r);
        }
        #pragma unroll
        for (int k = 0; k < 4; ++k) {
            float s = (lr & 4) ? v[k] : v[k + 4];
            float r = __shfl_xor(s, 4);
            v[k] = (lr & 4) ? fminf(v[k + 4], r) : fminf(v[k], r);
        }
        #pragma unroll
        for (int k = 0; k < 2; ++k) {
            float s = (lr & 2) ? v[k] : v[k + 2];
            float r = __shfl_xor(s, 2);
            v[k] = (lr & 2) ? fminf(v[k + 2], r) : fminf(v[k], r);
        }
        {
            float s = (lr & 1) ? v[0] : v[1];
            float r = __shfl_xor(s, 1);
            v[0] = (lr & 1) ? fminf(v[1], r) : fminf(v[0], r);
        }
        const int own_row = tm_base + wr + ((lr >> 2) << 4) + (lq << 2) + (lr & 3);

        float cp[4];
        #pragma unroll
        for (int ni = 0; ni < 4; ++ni) {
            float m = fmaf(-2.f, acc[0][ni][0], a2v[0][0]);
            #pragma unroll
            for (int mi = 0; mi < 4; ++mi)
                #pragma unroll
                for (int jj = 0; jj < 4; ++jj)
                    if (mi | jj) m = fminf(m, fmaf(-2.f, acc[mi][ni][jj], a2v[mi][jj]));
            cp[ni] = m;
        }
        #pragma unroll
        for (int k = 0; k < 2; ++k) {
            float s = (lane & 16) ? cp[k] : cp[k + 2];
            float r = __shfl_xor(s, 16);
            cp[k] = (lane & 16) ? fminf(cp[k + 2], r) : fminf(cp[k], r);
        }
        float cfin;
        {
            float s = (lane & 32) ? cp[0] : cp[1];
            float r = __shfl_xor(s, 32);
            cfin = (lane & 32) ? fminf(cp[1], r) : fminf(cp[0], r);
        }
        const int ni_own = ((lq & 1) << 1) | (lq >> 1);
        const int own_col = col_base + ni_own * 16 + lr;

        __syncthreads();

        atomicMin(&rowmin[own_row], fmap(v[0]));
        atomicMin(&colmin[own_col], fmap(cfin));
    }
}

__global__ void chamfer_finalize2(const unsigned* __restrict__ rowmin,
                                  const unsigned* __restrict__ colmin,
                                  const float* __restrict__ a2, const float* __restrict__ b2,
                                  float* __restrict__ out) {
    __shared__ double sred[16];
    int t = threadIdx.x;
    double s = 0.0;
    for (int i = t; i < N_PTS; i += 1024)
        s += ((double)funmap(rowmin[i]) + (double)a2[i])
           + ((double)funmap(colmin[i]) + (double)b2[i]);
    #pragma unroll
    for (int off = 32; off; off >>= 1) s += __shfl_down(s, off);
    if ((t & 63) == 0) sred[t >> 6] = s;
    __syncthreads();
    if (t == 0) {
        double tot = 0.0;
        #pragma unroll
        for (int i = 0; i < 16; ++i) tot += sred[i];
        out[0] = (float)(tot * (1.0 / (double)N_PTS));
    }
}

// ---------------------------------------------------------------------------
extern "C" void kernel_launch(void* const* d_in, const int* in_sizes, int n_in,
                              void* d_out, int out_size, void* d_ws, size_t ws_size,
                              hipStream_t stream) {
    const float* A = (const float*)d_in[0];
    const float* B = (const float*)d_in[1];
    float* out = (float*)d_out;
    char* ws = (char*)d_ws;

    const size_t MATSZ  = (size_t)N_PTS * DIM * sizeof(unsigned short);  // 4 MB
    const size_t PKSZ   = (size_t)N_PTS * 4;                             // 64 KB
    const size_t need13 = 2 * MATSZ + 2 * PKSZ + 8 * PKSZ + 64 * sizeof(double);

    const size_t need3  = 2 * MATSZ + 4 * (size_t)(1 << 16);             // ~8.65 MB

    if (ws_size >= need13) {
        unsigned short* Ax  = (unsigned short*)(ws);
        unsigned char*  Bt2 = (unsigned char*)(ws + MATSZ);
        unsigned* a2pack    = (unsigned*)(ws + 2 * MATSZ);
        unsigned* b2pack    = (unsigned*)(ws + 2 * MATSZ + PKSZ);
        unsigned* minbuf    = (unsigned*)(ws + 2 * MATSZ + 2 * PKSZ);
        unsigned* rowminS   = minbuf;                     // [4][N]
        unsigned* colminS   = minbuf + 4 * N_PTS;         // [4][N]
        double*   partials  = (double*)(ws + 2 * MATSZ + 10 * PKSZ);

        chamfer_prep13<<<(2 * N_PTS) / 4, 256, 0, stream>>>(A, B, Ax, Bt2, a2pack, b2pack, minbuf);
        chamfer_gemm_min13<<<2048, 256, 0, stream>>>(Ax, Bt2, a2pack, b2pack, rowminS, colminS);
        chamfer_partial13<<<64, 256, 0, stream>>>(rowminS, colminS, partials);
        chamfer_final13<<<1, 64, 0, stream>>>(partials, out);
    } else if (ws_size >= need3) {
        unsigned short* Abf = (unsigned short*)(ws);
        unsigned short* Bbf = (unsigned short*)(ws + MATSZ);
        float*    a2     = (float*)(ws + 2 * MATSZ);
        float*    b2     = (float*)(ws + 2 * MATSZ + (1 << 16));
        unsigned* rowmin = (unsigned*)(ws + 2 * MATSZ + (2 << 16));
        unsigned* colmin = (unsigned*)(ws + 2 * MATSZ + (3 << 16));

        chamfer_prep2<<<(2 * N_PTS) / 4, 256, 0, stream>>>(A, B, Abf, Bbf, a2, b2, rowmin, colmin);
        chamfer_gemm_min3<<<256, 512, 0, stream>>>(Abf, Bbf, a2, b2, rowmin, colmin);
        chamfer_finalize2<<<1, 1024, 0, stream>>>(rowmin, colmin, a2, b2, out);
    }
}

// Round 14
// 99.484 us; speedup vs baseline: 80.4460x; 1.9390x over previous
//
#include <hip/hip_runtime.h>
#include <hip/hip_bf16.h>

#define N_PTS 16384
#define DIM   128
#define KAUG  144            // 128 data + {1,1,a2hi,a2lo}/{b2hi,b2lo,1,1} + 12 zeros
#define ROWB  (KAUG * 2)     // 288 bytes per augmented row
#define NCHUNK 18            // 16B chunks per row

typedef __bf16 bf16x8 __attribute__((ext_vector_type(8)));
typedef float  f32x4  __attribute__((ext_vector_type(4)));
typedef float  f32x16 __attribute__((ext_vector_type(16)));

// Monotone map float -> uint so unsigned atomicMin == float min (handles negatives).
__device__ __forceinline__ unsigned fmap(float f) {
    unsigned u = __float_as_uint(f);
    return (u & 0x80000000u) ? ~u : (u | 0x80000000u);
}
__device__ __forceinline__ float funmap(unsigned u) {
    return __uint_as_float((u & 0x80000000u) ? (u & 0x7FFFFFFFu) : ~u);
}

__device__ __forceinline__ void gload_lds16(const void* g, void* l) {
    __builtin_amdgcn_global_load_lds(
        (const __attribute__((address_space(1))) void*)g,
        (__attribute__((address_space(3))) void*)l, 16, 0, 0);
}

// ---------------------------------------------------------------------------
// Prep: augmented bf16 rows, KAUG=144.
//   Ax[r] = [ bf16(-2*a[r][k]) (128) | 1, 1, a2hi, a2lo | zeros(12) ]
//   Bx[c] = [ bf16(   b[c][k]) (128) | b2hi, b2lo, 1, 1 | zeros(12) ]
// dot(Ax[r],Bx[c]) = dist^2. Also inits the 4*N min buffer.
// ---------------------------------------------------------------------------
__global__ void chamfer_prep5(const float* __restrict__ A, const float* __restrict__ B,
                              unsigned short* __restrict__ Ax, unsigned short* __restrict__ Bx,
                              unsigned* __restrict__ minbuf) {
    int gtid = blockIdx.x * 256 + threadIdx.x;
    if (gtid < 4 * N_PTS) minbuf[gtid] = 0xFFFFFFFFu;

    int wave = blockIdx.x * 4 + (threadIdx.x >> 6);
    int lane = threadIdx.x & 63;
    int isB  = wave >= N_PTS;
    int row  = isB ? (wave - N_PTS) : wave;
    const float* src = isB ? B : A;
    unsigned short* dst = isB ? Bx : Ax;

    float2 v = *reinterpret_cast<const float2*>(&src[(size_t)row * DIM + lane * 2]);

    float sc = isB ? 1.f : -2.f;
    __bf16 bx = (__bf16)(sc * v.x), by = (__bf16)(sc * v.y);
    ushort2 st;
    st.x = __builtin_bit_cast(unsigned short, bx);
    st.y = __builtin_bit_cast(unsigned short, by);
    *reinterpret_cast<ushort2*>(&dst[(size_t)row * KAUG + lane * 2]) = st;

    float s = fmaf(v.x, v.x, v.y * v.y);
    #pragma unroll
    for (int off = 1; off < 64; off <<= 1) s += __shfl_xor(s, off);

    __bf16 hb = (__bf16)s;
    float  hf = (float)hb;
    __bf16 lb = (__bf16)(s - hf);
    unsigned short hu = __builtin_bit_cast(unsigned short, hb);
    unsigned short lu = __builtin_bit_cast(unsigned short, lb);
    const unsigned short one = 0x3F80;

    if (lane < 8) {  // k = 128..143
        ushort2 tw; tw.x = 0; tw.y = 0;
        if (lane == 0) { tw.x = isB ? hu : one; tw.y = isB ? lu : one; }
        if (lane == 1) { tw.x = isB ? one : hu; tw.y = isB ? one : lu; }
        *reinterpret_cast<ushort2*>(&dst[(size_t)row * KAUG + 128 + lane * 2]) = tw;
    }
}

// ---------------------------------------------------------------------------
// GEMM+min v7 (FINAL, best measured: 99.6 us total / 89 us gemm):
// v5 structure + counted-vmcnt 2-deep pipeline (T3/T4) + setprio.
// 512 blocks x 256 threads (4 waves, 2x2), 32x32x16 MFMA, 2 blocks/CU.
// Main loop never drains vmcnt to 0: stage(t+2) issued right after barrier1,
// epilogue VALU runs under the in-flight loads, vmcnt(9) + barrier2 only
// requires t+1's loads (issued a full iteration earlier).
// C/D layout (32x32x16): col = lane&31, row = (reg&3) + 8*(reg>>2) + 4*hi.
// ---------------------------------------------------------------------------
__global__ __launch_bounds__(256, 2)
void chamfer_gemm_min7(const unsigned short* __restrict__ Ax,
                       const unsigned short* __restrict__ Bx,
                       unsigned* __restrict__ rowminS,    // [2][N_PTS]
                       unsigned* __restrict__ colminS) {  // [2][N_PTS]
    __shared__ __align__(16) unsigned char sB[2][36864];

    const int b   = blockIdx.x;
    const int tm  = (b >> 2) * 128;
    const int tn0 = (b & 3) * 32;

    const int t = threadIdx.x, w = t >> 6, lane = t & 63;
    const int ll = lane & 31, hi = lane >> 5;
    const int wr = (w >> 1) * 64, wc = (w & 1) * 64;

    // ---- A fragments -> registers: af[mi][ks], row = tm+wr+mi*32+ll ----
    bf16x8 af[2][9];
    #pragma unroll
    for (int mi = 0; mi < 2; ++mi) {
        const unsigned short* ap = Ax + (size_t)(tm + wr + mi * 32 + ll) * KAUG + hi * 8;
        #pragma unroll
        for (int ks = 0; ks < 9; ++ks)
            af[mi][ks] = *reinterpret_cast<const bf16x8*>(ap + ks * 16);
    }

    // ---- staging offsets (loop-invariant): 2304 chunks, 9 per thread ----
    int goff[9];
    #pragma unroll
    for (int j = 0; j < 9; ++j) {
        int chunk = j * 256 + t;
        int r = chunk / NCHUNK;
        int s = chunk - r * NCHUNK;
        int c = (s < 16) ? (s ^ (r & 7)) : (16 + ((s - 16) ^ (r & 1)));
        goff[j] = r * KAUG + c * 8;
    }

    // ---- prologue: stage tiles tn0 -> buf0 and tn0+1 -> buf1 ----
    {
        const unsigned short* bp0 = Bx + (size_t)tn0 * 128 * KAUG;
        const unsigned short* bp1 = Bx + (size_t)(tn0 + 1) * 128 * KAUG;
        #pragma unroll
        for (int j = 0; j < 9; ++j)
            gload_lds16(bp0 + goff[j], sB[0] + (j * 256 + t) * 16);
        #pragma unroll
        for (int j = 0; j < 9; ++j)
            gload_lds16(bp1 + goff[j], sB[1] + (j * 256 + t) * 16);
    }
    asm volatile("s_waitcnt vmcnt(9)" ::: "memory");   // buf0's 9 loads done
    __builtin_amdgcn_sched_barrier(0);
    __builtin_amdgcn_s_barrier();
    __builtin_amdgcn_sched_barrier(0);

    float rmin_part[32];
    #pragma unroll
    for (int k = 0; k < 32; ++k) rmin_part[k] = 3.4e38f;

    const int rA = wc + ll;          // nj=0 row in tile
    const int rB = wc + 32 + ll;     // nj=1 row in tile

    for (int it = 0; it < 32; ++it) {
        const int cur = it & 1;
        const int tn  = tn0 + it;

        // ---- MFMA: 64x64 per wave as 2x2 32x32 tiles, 9 k-steps ----
        __builtin_amdgcn_s_setprio(1);
        f32x16 acc[2][2] = {};
        #pragma unroll
        for (int ks = 0; ks < 9; ++ks) {
            const int c = ks * 2 + hi;
            const int sA0 = (c < 16) ? (c ^ (rA & 7)) : (16 + ((c - 16) ^ (rA & 1)));
            const int sB1 = (c < 16) ? (c ^ (rB & 7)) : (16 + ((c - 16) ^ (rB & 1)));
            bf16x8 b0 = *reinterpret_cast<const bf16x8*>(&sB[cur][rA * ROWB + sA0 * 16]);
            bf16x8 b1 = *reinterpret_cast<const bf16x8*>(&sB[cur][rB * ROWB + sB1 * 16]);
            #pragma unroll
            for (int mi = 0; mi < 2; ++mi) {
                acc[mi][0] = __builtin_amdgcn_mfma_f32_32x32x16_bf16(af[mi][ks], b0, acc[mi][0], 0, 0, 0);
                acc[mi][1] = __builtin_amdgcn_mfma_f32_32x32x16_bf16(af[mi][ks], b1, acc[mi][1], 0, 0, 0);
            }
        }
        __builtin_amdgcn_s_setprio(0);

        // ---- barrier1: all waves' ds_reads of sB[cur] retired ----
        __builtin_amdgcn_sched_barrier(0);
        __builtin_amdgcn_s_barrier();
        __builtin_amdgcn_sched_barrier(0);

        // ---- stage tile tn+2 into the just-consumed buffer (stays in flight) ----
        if (it + 2 < 32) {
            const unsigned short* bp = Bx + (size_t)(tn + 2) * 128 * KAUG;
            #pragma unroll
            for (int j = 0; j < 9; ++j)
                gload_lds16(bp + goff[j], sB[cur] + (j * 256 + t) * 16);
        }

        // ---- epilogue (registers/VALU only) under the in-flight loads ----
        #pragma unroll
        for (int mi = 0; mi < 2; ++mi)
            #pragma unroll
            for (int reg = 0; reg < 16; ++reg)
                rmin_part[mi * 16 + reg] =
                    fminf(rmin_part[mi * 16 + reg], fminf(acc[mi][0][reg], acc[mi][1][reg]));

        float cm0 = acc[0][0][0], cm1 = acc[0][1][0];
        #pragma unroll
        for (int mi = 0; mi < 2; ++mi)
            #pragma unroll
            for (int reg = 0; reg < 16; ++reg) {
                if (mi | reg) {
                    cm0 = fminf(cm0, acc[mi][0][reg]);
                    cm1 = fminf(cm1, acc[mi][1][reg]);
                }
            }
        cm0 = fminf(cm0, __shfl_xor(cm0, 32));
        cm1 = fminf(cm1, __shfl_xor(cm1, 32));
        float cmSel = hi ? cm1 : cm0;
        const int own_col = tn * 128 + wc + hi * 32 + ll;

        // ---- counted wait (never 0 until the tail) + barrier2 ----
        if (it < 30) { asm volatile("s_waitcnt vmcnt(9)" ::: "memory"); }
        else         { asm volatile("s_waitcnt vmcnt(0)" ::: "memory"); }
        __builtin_amdgcn_sched_barrier(0);
        __builtin_amdgcn_s_barrier();
        __builtin_amdgcn_sched_barrier(0);

        // atomic fires after barrier2; its latency hides under the next tile
        atomicMin(&colminS[(size_t)(w >> 1) * N_PTS + own_col], fmap(cmSel));
    }

    // ---- final row reduce-scatter: 32 vars over 32 ll-lanes, 5 stages ----
    #pragma unroll
    for (int s = 16; s >= 1; s >>= 1) {
        #pragma unroll
        for (int k = 0; k < 16; ++k) {
            if (k < s) {
                float snd = (ll & s) ? rmin_part[k] : rmin_part[k + s];
                float r = __shfl_xor(snd, s);
                rmin_part[k] = (ll & s) ? fminf(rmin_part[k + s], r) : fminf(rmin_part[k], r);
            }
        }
    }
    const int own_row = tm + wr + ((ll >> 4) << 5) + (ll & 3) + (((ll >> 2) & 3) << 3) + (hi << 2);
    atomicMin(&rowminS[(size_t)(w & 1) * N_PTS + own_row], fmap(rmin_part[0]));
}

// ---------------------------------------------------------------------------
// Finalize, two-stage: 64-block partial double sums, then one tiny kernel.
// ---------------------------------------------------------------------------
__global__ void chamfer_partial7(const unsigned* __restrict__ rowminS,
                                 const unsigned* __restrict__ colminS,
                                 double* __restrict__ partials) {
    __shared__ double sred[4];
    int t = threadIdx.x;
    int i = blockIdx.x * 256 + t;
    unsigned rm = min(rowminS[i], rowminS[i + N_PTS]);
    unsigned cm = min(colminS[i], colminS[i + N_PTS]);
    double s = (double)funmap(rm) + (double)funmap(cm);
    #pragma unroll
    for (int off = 32; off; off >>= 1) s += __shfl_down(s, off);
    if ((t & 63) == 0) sred[t >> 6] = s;
    __syncthreads();
    if (t == 0) partials[blockIdx.x] = sred[0] + sred[1] + sred[2] + sred[3];
}

__global__ void chamfer_final7(const double* __restrict__ partials,
                               float* __restrict__ out) {
    int t = threadIdx.x;   // 64 threads
    double s = partials[t];
    #pragma unroll
    for (int off = 32; off; off >>= 1) s += __shfl_down(s, off);
    if (t == 0) out[0] = (float)(s * (1.0 / (double)N_PTS));
}

// ---------------------------------------------------------------------------
// Fallback path = round-3 kernels (known-passing) if ws too small.
// ---------------------------------------------------------------------------
__global__ void chamfer_prep2(const float* __restrict__ A, const float* __restrict__ B,
                              unsigned short* __restrict__ Abf, unsigned short* __restrict__ Bbf,
                              float* __restrict__ a2, float* __restrict__ b2,
                              unsigned* __restrict__ rowmin, unsigned* __restrict__ colmin) {
    int wave = blockIdx.x * 4 + (threadIdx.x >> 6);
    int lane = threadIdx.x & 63;
    int isB  = wave >= N_PTS;
    int row  = isB ? (wave - N_PTS) : wave;
    const float* src = isB ? B : A;
    unsigned short* dst = isB ? Bbf : Abf;

    float2 v = *reinterpret_cast<const float2*>(&src[(size_t)row * DIM + lane * 2]);
    __bf16 bx = (__bf16)v.x, by = (__bf16)v.y;
    ushort2 st;
    st.x = __builtin_bit_cast(unsigned short, bx);
    st.y = __builtin_bit_cast(unsigned short, by);
    *reinterpret_cast<ushort2*>(&dst[(size_t)row * DIM + lane * 2]) = st;

    float s = fmaf(v.x, v.x, v.y * v.y);
    #pragma unroll
    for (int off = 32; off; off >>= 1) s += __shfl_down(s, off);
    if (lane == 0) {
        if (isB) { b2[row] = s; colmin[row] = 0xFFFFFFFFu; }
        else     { a2[row] = s; rowmin[row] = 0xFFFFFFFFu; }
    }
}

__global__ __launch_bounds__(512, 2)
void chamfer_gemm_min3(const unsigned short* __restrict__ Abf, const unsigned short* __restrict__ Bbf,
                       const float* __restrict__ a2, const float* __restrict__ b2,
                       unsigned* __restrict__ rowmin, unsigned* __restrict__ colmin) {
    __shared__ __align__(16) unsigned char sA[65536];
    __shared__ __align__(16) unsigned char sB2[2][32768];

    const int b = blockIdx.x;
    const int tm_base = (b >> 2) * 256;
    const int tn0 = (b & 3) * 32;

    const int t = threadIdx.x;
    const int w = t >> 6, lane = t & 63;
    const int lq = lane >> 4, lr = lane & 15;
    const int wr = (w >> 1) * 64;
    const int wc = (w & 1) * 64;

    #pragma unroll
    for (int jj = 0; jj < 8; ++jj) {
        int chunk = ((w << 3) + jj) * 64 + lane;
        int r = chunk >> 4, kc = (chunk & 15) ^ (r & 7);
        gload_lds16(Abf + (size_t)(tm_base + r) * DIM + kc * 8, sA + chunk * 16);
    }
    #pragma unroll
    for (int jj = 0; jj < 4; ++jj) {
        int chunk = ((w << 2) + jj) * 64 + lane;
        int r = chunk >> 4, kc = (chunk & 15) ^ (r & 7);
        gload_lds16(Bbf + (size_t)(tn0 * 128 + r) * DIM + kc * 8, sB2[0] + chunk * 16);
    }

    float a2v[4][4];
    #pragma unroll
    for (int mi = 0; mi < 4; ++mi) {
        float4 q = *reinterpret_cast<const float4*>(&a2[tm_base + wr + mi * 16 + lq * 4]);
        a2v[mi][0] = q.x; a2v[mi][1] = q.y; a2v[mi][2] = q.z; a2v[mi][3] = q.w;
    }
    __syncthreads();

    for (int it = 0; it < 32; ++it) {
        const int cur = it & 1;
        const int tn = tn0 + it;

        if (it + 1 < 32) {
            #pragma unroll
            for (int jj = 0; jj < 4; ++jj) {
                int chunk = ((w << 2) + jj) * 64 + lane;
                int r = chunk >> 4, kc = (chunk & 15) ^ (r & 7);
                gload_lds16(Bbf + (size_t)((tn + 1) * 128 + r) * DIM + kc * 8,
                            sB2[cur ^ 1] + chunk * 16);
            }
        }

        f32x4 acc[4][4] = {};
        #pragma unroll
        for (int ks = 0; ks < 4; ++ks) {
            const int kc = ks * 4 + lq;
            bf16x8 af2[4], bfr[4];
            #pragma unroll
            for (int mi = 0; mi < 4; ++mi) {
                int r = wr + mi * 16 + lr;
                af2[mi] = *reinterpret_cast<const bf16x8*>(&sA[r * 256 + ((kc * 16) ^ ((r & 7) << 4))]);
            }
            #pragma unroll
            for (int ni = 0; ni < 4; ++ni) {
                int r = wc + ni * 16 + lr;
                bfr[ni] = *reinterpret_cast<const bf16x8*>(&sB2[cur][r * 256 + ((kc * 16) ^ ((r & 7) << 4))]);
            }
            #pragma unroll
            for (int mi = 0; mi < 4; ++mi)
                #pragma unroll
                for (int ni = 0; ni < 4; ++ni)
                    acc[mi][ni] = __builtin_amdgcn_mfma_f32_16x16x32_bf16(af2[mi], bfr[ni], acc[mi][ni], 0, 0, 0);
        }

        const int col_base = tn * 128 + wc;
        float b2v[4];
        #pragma unroll
        for (int ni = 0; ni < 4; ++ni) b2v[ni] = b2[col_base + ni * 16 + lr];

        float v[16];
        #pragma unroll
        for (int mi = 0; mi < 4; ++mi) {
            #pragma unroll
            for (int jj = 0; jj < 4; ++jj) {
                float m = fmaf(-2.f, acc[mi][0][jj], b2v[0]);
                m = fminf(m, fmaf(-2.f, acc[mi][1][jj], b2v[1]));
                m = fminf(m, fmaf(-2.f, acc[mi][2][jj], b2v[2]));
                m = fminf(m, fmaf(-2.f, acc[mi][3][jj], b2v[3]));
                v[mi * 4 + jj] = m;
            }
        }
        #pragma unroll
        for (int k = 0; k < 8; ++k) {
            float s = (lr & 8) ? v[k] : v[k + 8];
            float r = __shfl_xor(s, 8);
            v[k] = (lr & 8) ? fminf(v[k + 8], r) : fminf(v[k], r);
        }
        #pragma unroll
        for (int k = 0; k < 4; ++k) {
            float s = (lr & 4) ? v[k] : v[k + 4];
            float r = __shfl_xor(s, 4);
            v[k] = (lr & 4) ? fminf(v[k + 4], r) : fminf(v[k], r);
        }
        #pragma unroll
        for (int k = 0; k < 2; ++k) {
            float s = (lr & 2) ? v[k] : v[k + 2];
            float r = __shfl_xor(s, 2);
            v[k] = (lr & 2) ? fminf(v[k + 2], r) : fminf(v[k], r);
        }
        {
            float s = (lr & 1) ? v[0] : v[1];
            float r = __shfl_xor(s, 1);
            v[0] = (lr & 1) ? fminf(v[1], r) : fminf(v[0], r);
        }
        const int own_row = tm_base + wr + ((lr >> 2) << 4) + (lq << 2) + (lr & 3);

        float cp[4];
        #pragma unroll
        for (int ni = 0; ni < 4; ++ni) {
            float m = fmaf(-2.f, acc[0][ni][0], a2v[0][0]);
            #pragma unroll
            for (int mi = 0; mi < 4; ++mi)
                #pragma unroll
                for (int jj = 0; jj < 4; ++jj)
                    if (mi | jj) m = fminf(m, fmaf(-2.f, acc[mi][ni][jj], a2v[mi][jj]));
            cp[ni] = m;
        }
        #pragma unroll
        for (int k = 0; k < 2; ++k) {
            float s = (lane & 16) ? cp[k] : cp[k + 2];
            float r = __shfl_xor(s, 16);
            cp[k] = (lane & 16) ? fminf(cp[k + 2], r) : fminf(cp[k], r);
        }
        float cfin;
        {
            float s = (lane & 32) ? cp[0] : cp[1];
            float r = __shfl_xor(s, 32);
            cfin = (lane & 32) ? fminf(cp[1], r) : fminf(cp[0], r);
        }
        const int ni_own = ((lq & 1) << 1) | (lq >> 1);
        const int own_col = col_base + ni_own * 16 + lr;

        __syncthreads();

        atomicMin(&rowmin[own_row], fmap(v[0]));
        atomicMin(&colmin[own_col], fmap(cfin));
    }
}

__global__ void chamfer_finalize2(const unsigned* __restrict__ rowmin,
                                  const unsigned* __restrict__ colmin,
                                  const float* __restrict__ a2, const float* __restrict__ b2,
                                  float* __restrict__ out) {
    __shared__ double sred[16];
    int t = threadIdx.x;
    double s = 0.0;
    for (int i = t; i < N_PTS; i += 1024)
        s += ((double)funmap(rowmin[i]) + (double)a2[i])
           + ((double)funmap(colmin[i]) + (double)b2[i]);
    #pragma unroll
    for (int off = 32; off; off >>= 1) s += __shfl_down(s, off);
    if ((t & 63) == 0) sred[t >> 6] = s;
    __syncthreads();
    if (t == 0) {
        double tot = 0.0;
        #pragma unroll
        for (int i = 0; i < 16; ++i) tot += sred[i];
        out[0] = (float)(tot * (1.0 / (double)N_PTS));
    }
}

// ---------------------------------------------------------------------------
extern "C" void kernel_launch(void* const* d_in, const int* in_sizes, int n_in,
                              void* d_out, int out_size, void* d_ws, size_t ws_size,
                              hipStream_t stream) {
    const float* A = (const float*)d_in[0];
    const float* B = (const float*)d_in[1];
    float* out = (float*)d_out;
    char* ws = (char*)d_ws;

    const size_t SZ7   = (size_t)N_PTS * KAUG * sizeof(unsigned short);  // 4.72 MB
    const size_t need7 = 2 * SZ7 + 4 * (size_t)N_PTS * 4 + 64 * sizeof(double);

    const size_t BF    = (size_t)N_PTS * DIM * sizeof(unsigned short);   // 4 MB
    const size_t need3 = 2 * BF + 4 * (size_t)(1 << 16);                 // ~8.65 MB

    if (ws_size >= need7) {
        unsigned short* Ax = (unsigned short*)(ws);
        unsigned short* Bx = (unsigned short*)(ws + SZ7);
        unsigned* minbuf   = (unsigned*)(ws + 2 * SZ7);
        unsigned* rowminS  = minbuf;                     // [2][N]
        unsigned* colminS  = minbuf + 2 * N_PTS;         // [2][N]
        double*   partials = (double*)(ws + 2 * SZ7 + 4 * (size_t)N_PTS * 4);

        chamfer_prep5<<<(2 * N_PTS) / 4, 256, 0, stream>>>(A, B, Ax, Bx, minbuf);
        chamfer_gemm_min7<<<512, 256, 0, stream>>>(Ax, Bx, rowminS, colminS);
        chamfer_partial7<<<64, 256, 0, stream>>>(rowminS, colminS, partials);
        chamfer_final7<<<1, 64, 0, stream>>>(partials, out);
    } else if (ws_size >= need3) {
        unsigned short* Abf = (unsigned short*)(ws);
        unsigned short* Bbf = (unsigned short*)(ws + BF);
        float*    a2     = (float*)(ws + 2 * BF);
        float*    b2     = (float*)(ws + 2 * BF + (1 << 16));
        unsigned* rowmin = (unsigned*)(ws + 2 * BF + (2 << 16));
        unsigned* colmin = (unsigned*)(ws + 2 * BF + (3 << 16));

        chamfer_prep2<<<(2 * N_PTS) / 4, 256, 0, stream>>>(A, B, Abf, Bbf, a2, b2, rowmin, colmin);
        dim3 grid(N_PTS / 128, N_PTS / 128);
        chamfer_gemm_min3<<<256, 512, 0, stream>>>(Abf, Bbf, a2, b2, rowmin, colmin);
        chamfer_finalize2<<<1, 1024, 0, stream>>>(rowmin, colmin, a2, b2, out);
    }
}